// Round 5
// baseline (5275.847 us; speedup 1.0000x reference)
//
#include <hip/hip_runtime.h>
#include <stdint.h>

#define SEQ    512
#define NBATCH 64
#define HID    1024
#define GDIM   4096
#define SENT32 0x7F7F7F7Fu

typedef __attribute__((ext_vector_type(4))) float          f32x4;
typedef __attribute__((ext_vector_type(8))) short          s16x8;
typedef __attribute__((ext_vector_type(4))) unsigned short u16x4;
typedef __attribute__((ext_vector_type(4))) unsigned int   u32x4;

#define MFMA_BF16(a,b,c) __builtin_amdgcn_mfma_f32_16x16x32_bf16((a),(b),(c),0,0,0)

__device__ __forceinline__ unsigned short f2bf(float f){
  union { float f; unsigned u; } v; v.f = f;
  unsigned r = v.u + 0x7fffu + ((v.u >> 16) & 1u);
  return (unsigned short)(r >> 16);
}

__device__ __forceinline__ void gload_lds16(const void* g, void* l){
  __builtin_amdgcn_global_load_lds((const __attribute__((address_space(1))) void*)g,
                                   (__attribute__((address_space(3))) void*)l,
                                   16, 0, 0);
}

// ---------------- fp32 -> bf16 bulk convert (n4 = elements/4) ----------------
__global__ __launch_bounds__(256) void cvt_bf16(const float* __restrict__ s,
                                                unsigned short* __restrict__ d, int n4){
  int i = blockIdx.x*256 + threadIdx.x;
  if (i >= n4) return;
  f32x4 v = *(const f32x4*)(s + (size_t)i*4);
  u16x4 o;
  o[0]=f2bf(v[0]); o[1]=f2bf(v[1]); o[2]=f2bf(v[2]); o[3]=f2bf(v[3]);
  *(u16x4*)(d + (size_t)i*4) = o;
}

// ---------------- init: h0 -> h_hist slot 0 (bf16, SWIZZLED), c0 -> cstate ----
// slot layout: u16 idx = b*1024 + ((chunk ^ (b&7))*8) + (k&7), chunk = k>>3
__global__ __launch_bounds__(256) void init_state(const float* __restrict__ h0,
                                                  const float* __restrict__ c0,
                                                  unsigned short* __restrict__ hhist,
                                                  float* __restrict__ cstate){
  int i = blockIdx.x*256 + threadIdx.x;   // 65536 total
  int b = i >> 10, c = i & 1023;
  int sw = (c >> 3) ^ (b & 7);
  hhist[b*1024 + sw*8 + (c & 7)] = f2bf(h0[i]);
  cstate[i] = c0[i];
}

// ---------------- x_proj GEMM: C[M][4096] = A[M][1024] * Bw[4096][1024]^T + bias ----
__global__ __launch_bounds__(256,1) void gemm_xproj(
    const unsigned short* __restrict__ A,   // bf16 [M][1024]
    const unsigned short* __restrict__ Bw,  // bf16 [4096][1024]
    const float* __restrict__ bih, const float* __restrict__ bhh,
    float* __restrict__ C, int M)
{
  __shared__ unsigned short Al[2][128*64];
  __shared__ unsigned short Bl[2][128*64];

  const int bm = blockIdx.x >> 5;
  const int bn = blockIdx.x & 31;
  const int tid = threadIdx.x;
  const int wv = tid >> 6, l = tid & 63;
  const int wm = wv >> 1, wn = wv & 1;
  const int c16 = l & 15, rq = l >> 4;

  const unsigned short* Ab = A  + (size_t)bm*128*1024;
  const unsigned short* Bb = Bw + (size_t)bn*128*1024;

  f32x4 acc[4][4];
#pragma unroll
  for (int i=0;i<4;++i)
#pragma unroll
    for (int j=0;j<4;++j) acc[i][j] = (f32x4){0.f,0.f,0.f,0.f};

  auto stage = [&](int buf, int kt){
    const int k0 = kt*64;
    const int rsub = wv*8 + (l>>3);
    const int col  = (l&7)*8;
#pragma unroll
    for (int is=0; is<4; ++is){
      const int row = is*32 + rsub;
      gload_lds16(Ab + (size_t)row*1024 + k0 + col, &Al[buf][row*64 + col]);
      gload_lds16(Bb + (size_t)row*1024 + k0 + col, &Bl[buf][row*64 + col]);
    }
  };

  stage(0, 0);
  asm volatile("s_waitcnt vmcnt(0)" ::: "memory");
  __syncthreads();

  for (int kt = 0; kt < 16; ++kt){
    const int cur = kt & 1;
    if (kt < 15) stage(cur^1, kt+1);
#pragma unroll
    for (int ks=0; ks<2; ++ks){
      s16x8 afr[4], bfr[4];
#pragma unroll
      for (int mi=0;mi<4;++mi)
        afr[mi] = *(const s16x8*)&Al[cur][(wm*64 + mi*16 + c16)*64 + ks*32 + rq*8];
#pragma unroll
      for (int ni=0;ni<4;++ni)
        bfr[ni] = *(const s16x8*)&Bl[cur][(wn*64 + ni*16 + c16)*64 + ks*32 + rq*8];
#pragma unroll
      for (int mi=0;mi<4;++mi)
#pragma unroll
        for (int ni=0;ni<4;++ni)
          acc[mi][ni] = MFMA_BF16(afr[mi], bfr[ni], acc[mi][ni]);
    }
    asm volatile("s_waitcnt vmcnt(0)" ::: "memory");
    __syncthreads();
  }

  const int crow0 = bm*128 + wm*64;
  const int ccol0 = bn*128 + wn*64;
#pragma unroll
  for (int ni=0;ni<4;++ni){
    const int col = ccol0 + ni*16 + c16;
    const float bsum = bih[col] + bhh[col];
#pragma unroll
    for (int mi=0;mi<4;++mi){
      const int row = crow0 + mi*16 + rq*4;
#pragma unroll
      for (int r=0;r<4;++r)
        C[(size_t)(row+r)*GDIM + col] = acc[mi][ni][r] + bsum;
    }
  }
}

// ---------------- persistent recurrence over one chunk of timesteps ----------------
// 64 blocks x 512 threads. Block b owns hidden cols [16b,16b+16) -> 64 gate rows.
// Dataflow sync: h_hist slot t+1 is fresh memory pre-filled with sentinel
// (0x7F7F per u16). Producers store h write-through (sc0 sc1), fire-and-forget.
// Consumers load chunks (sc0 sc1) and retry any 16B chunk still reading
// sentinel. No flags, no barrier, no drains -- one store-visible + one load
// round-trip per step.
__global__ __launch_bounds__(512,2) void lstm_rec(
    const unsigned short* __restrict__ whhb,   // bf16 [4096][1024]
    const float* __restrict__ xproj,           // fp32 [nsteps*64][4096]
    unsigned short* __restrict__ hhist,        // bf16 [SEQ+1][64*1024] (swizzled)
    float* __restrict__ cstate,                // fp32 [64*1024]
    float* __restrict__ outp,                  // fp32 d_out base
    int t0, int nsteps)
{
  const int tid = threadIdx.x;
  const int wv = tid >> 6, l = tid & 63;
  const int kh = wv & 1, rh = (wv >> 1) & 1, mh = wv >> 2;
  const int c16 = l & 15, rq = l >> 4;
  const int hc0 = blockIdx.x * 16;
  const int eb = tid >> 3, ej = tid & 7;      // epilogue (batch, col-pair base)

  __shared__ s16x8 hls4[8192];                          // 128 KB staged h
  __shared__ float part[64*66];                         // 16.9 KB partials
  __shared__ __align__(16) unsigned short hsh[64*16];   // 2 KB h bf16 staging

  // ---- W_hh slice -> registers: breg[nt][ks], gate row n = rh*32+nt*16+c16,
  //      whh row = (n&3)*HID + hc0 + (n>>2); k = kh*512 + ks*32 + rq*8
  s16x8 breg[2][16];
#pragma unroll
  for (int nt = 0; nt < 2; ++nt)
#pragma unroll
    for (int ks = 0; ks < 16; ++ks){
      const int n = rh*32 + nt*16 + c16;
      const int grow = (n & 3)*HID + hc0 + (n >> 2);
      const int k = kh*512 + ks*32 + rq*8;
      breg[nt][ks] = *(const s16x8*)(whhb + (size_t)grow*HID + k);
    }

  float creg0 = cstate[(size_t)eb*HID + hc0 + ej];
  float creg1 = cstate[(size_t)eb*HID + hc0 + ej + 8];
  float xpA[4], xpB[4];
#pragma unroll
  for (int g = 0; g < 4; ++g){
    xpA[g] = xproj[(size_t)eb*GDIM + g*HID + hc0 + ej];
    xpB[g] = xproj[(size_t)eb*GDIM + g*HID + hc0 + ej + 8];
  }

  for (int t = t0; t < t0 + nsteps; ++t){
    // ---- stage h slot t: 16 x 16B per thread, LLC loads with sentinel retry
    {
      const char* hsrc = (const char*)(hhist + (size_t)t*65536) + tid*16;
      u32x4 tmp[16];
#define SL(I) asm volatile("global_load_dwordx4 %0, %1, off sc0 sc1" \
                           : "=v"(tmp[I]) : "v"(hsrc + (I)*8192))
      SL(0); SL(1); SL(2); SL(3); SL(4); SL(5); SL(6); SL(7);
      SL(8); SL(9); SL(10); SL(11); SL(12); SL(13); SL(14); SL(15);
      unsigned mask = 0xFFFFu;
      int rounds = 0;
      for (;;){
        asm volatile("s_waitcnt vmcnt(0)" ::: "memory");
        __builtin_amdgcn_sched_barrier(0);
        unsigned nm = 0;
#pragma unroll
        for (int i = 0; i < 16; ++i)
          if (mask & (1u << i)){
            if (tmp[i][0]==SENT32 || tmp[i][1]==SENT32 ||
                tmp[i][2]==SENT32 || tmp[i][3]==SENT32) nm |= 1u << i;
          }
        mask = nm;
        if (!mask || ++rounds > (1<<16)) break;
        if (rounds > 8) __builtin_amdgcn_s_sleep(1);
#pragma unroll
        for (int i = 0; i < 16; ++i)
          if (mask & (1u << i)){
            switch(i){
              case 0: SL(0); break;  case 1: SL(1); break;
              case 2: SL(2); break;  case 3: SL(3); break;
              case 4: SL(4); break;  case 5: SL(5); break;
              case 6: SL(6); break;  case 7: SL(7); break;
              case 8: SL(8); break;  case 9: SL(9); break;
              case 10: SL(10); break; case 11: SL(11); break;
              case 12: SL(12); break; case 13: SL(13); break;
              case 14: SL(14); break; case 15: SL(15); break;
            }
          }
      }
#undef SL
#pragma unroll
      for (int it = 0; it < 16; ++it)
        hls4[it*512 + tid] = __builtin_bit_cast(s16x8, tmp[it]);
    }
    __syncthreads();

    // ---- MFMA: acc[msub][nt] over this wave's (batch-half, row-half, K-half)
    f32x4 acc[2][2];
#pragma unroll
    for (int ms = 0; ms < 2; ++ms)
#pragma unroll
      for (int nt = 0; nt < 2; ++nt) acc[ms][nt] = (f32x4){0.f,0.f,0.f,0.f};

#pragma unroll
    for (int ms = 0; ms < 2; ++ms){
      const int bl = mh*32 + ms*16 + c16;       // batch row in LDS
      const int bsw = bl & 7;
      s16x8 af[16];
#pragma unroll
      for (int ks = 0; ks < 16; ++ks)
        af[ks] = hls4[bl*128 + ((kh*64 + ks*4 + rq) ^ bsw)];
#pragma unroll
      for (int ks = 0; ks < 16; ++ks){
        acc[ms][0] = MFMA_BF16(af[ks], breg[0][ks], acc[ms][0]);
        acc[ms][1] = MFMA_BF16(af[ks], breg[1][ks], acc[ms][1]);
      }
    }

    // ---- K-half reduction through LDS: kh=0 writes, kh=1 adds
    if (kh == 0){
#pragma unroll
      for (int ms = 0; ms < 2; ++ms)
#pragma unroll
        for (int nt = 0; nt < 2; ++nt)
#pragma unroll
          for (int r = 0; r < 4; ++r)
            part[(mh*32 + ms*16 + rq*4 + r)*66 + rh*32 + nt*16 + c16] = acc[ms][nt][r];
    }
    __syncthreads();
    if (kh == 1){
#pragma unroll
      for (int ms = 0; ms < 2; ++ms)
#pragma unroll
        for (int nt = 0; nt < 2; ++nt)
#pragma unroll
          for (int r = 0; r < 4; ++r)
            part[(mh*32 + ms*16 + rq*4 + r)*66 + rh*32 + nt*16 + c16] += acc[ms][nt][r];
    }
    __syncthreads();

    // ---- epilogue: every thread handles (eb, ej) and (eb, ej+8)
    {
      const float vi0 = part[eb*66 + ej*4 + 0] + xpA[0];
      const float vf0 = part[eb*66 + ej*4 + 1] + xpA[1];
      const float vg0 = part[eb*66 + ej*4 + 2] + xpA[2];
      const float vo0 = part[eb*66 + ej*4 + 3] + xpA[3];
      const float vi1 = part[eb*66 + (ej+8)*4 + 0] + xpB[0];
      const float vf1 = part[eb*66 + (ej+8)*4 + 1] + xpB[1];
      const float vg1 = part[eb*66 + (ej+8)*4 + 2] + xpB[2];
      const float vo1 = part[eb*66 + (ej+8)*4 + 3] + xpB[3];

      const float i0 = 1.f/(1.f + __expf(-vi0)), f0 = 1.f/(1.f + __expf(-vf0));
      const float g0 = tanhf(vg0),               o0 = 1.f/(1.f + __expf(-vo0));
      const float i1 = 1.f/(1.f + __expf(-vi1)), f1 = 1.f/(1.f + __expf(-vf1));
      const float g1 = tanhf(vg1),               o1 = 1.f/(1.f + __expf(-vo1));
      creg0 = f0*creg0 + i0*g0;
      creg1 = f1*creg1 + i1*g1;
      const float h0 = o0 * tanhf(creg0);
      const float h1 = o1 * tanhf(creg1);

      const size_t oidx = (size_t)eb*HID + hc0 + ej;
      outp[(size_t)t*65536 + oidx]     = h0;
      outp[(size_t)t*65536 + oidx + 8] = h1;
      hsh[eb*16 + ej]     = f2bf(h0);
      hsh[eb*16 + ej + 8] = f2bf(h1);
      if (t == SEQ-1){
        outp[(size_t)SEQ*65536 + oidx]             = h0;
        outp[(size_t)SEQ*65536 + oidx + 8]         = h1;
        outp[(size_t)SEQ*65536 + 65536 + oidx]     = creg0;
        outp[(size_t)SEQ*65536 + 65536 + oidx + 8] = creg1;
      }
      // prefetch next step's xproj (overlaps store latency + next poll)
      if (t+1 < t0 + nsteps){
        const size_t xrow = (size_t)(t+1 - t0)*NBATCH + eb;
#pragma unroll
        for (int g = 0; g < 4; ++g){
          xpA[g] = xproj[xrow*GDIM + g*HID + hc0 + ej];
          xpB[g] = xproj[xrow*GDIM + g*HID + hc0 + ej + 8];
        }
      }
    }
    __syncthreads();                         // hsh visible

    // ---- swizzled h store to slot t+1: 128 threads x 16B, write-through,
    //      fire-and-forget (data IS the flag)
    if (tid < 128){
      const int b = tid >> 1, half = tid & 1;
      const int swz = (blockIdx.x*2 + half) ^ (b & 7);
      const unsigned short* hp = hhist + (size_t)(t+1)*65536 + (size_t)b*HID + swz*8;
      s16x8 hv = *(const s16x8*)&hsh[b*16 + half*8];
      asm volatile("global_store_dwordx4 %0, %1, off sc0 sc1"
                   :: "v"(hp), "v"(hv) : "memory");
    }
    // no barrier: hsh/hls4 rewrite is gated by the next stage's __syncthreads
    // (waves past the store) and the value read from LDS is already in hv.
    __syncthreads();
  }

  cstate[(size_t)eb*HID + hc0 + ej]     = creg0;
  cstate[(size_t)eb*HID + hc0 + ej + 8] = creg1;
}

// ---------------------------------------------------------------------------
extern "C" void kernel_launch(void* const* d_in, const int* in_sizes, int n_in,
                              void* d_out, int out_size, void* d_ws, size_t ws_size,
                              hipStream_t stream)
{
  const float* inp = (const float*)d_in[0];
  const float* wih = (const float*)d_in[1];
  const float* whh = (const float*)d_in[2];
  const float* bih = (const float*)d_in[3];
  const float* bhh = (const float*)d_in[4];
  const float* h0  = (const float*)d_in[5];
  const float* c0  = (const float*)d_in[6];
  float* outp = (float*)d_out;

  auto alignup = [](size_t x){ return (x + 255) & ~(size_t)255; };
  const size_t hhist_bytes = (size_t)(SEQ+1)*65536*2;   // 67 MB
  auto need = [&](size_t ch)->size_t{
    size_t s = 0;
    s += alignup(ch*64*4096*4);          // xproj chunk
    s += alignup(ch*64*1024*2);          // in_bf16 chunk
    s += alignup((size_t)4096*1024*2);   // wih_bf16
    s += alignup((size_t)4096*1024*2);   // whh_bf16
    s += alignup(hhist_bytes);           // h history (sentinel-filled)
    s += alignup((size_t)64*1024*4);     // cstate
    return s;
  };
  int CH = 512;
  while (CH > 2 && need(CH) > ws_size) CH >>= 1;

  char* w = (char*)d_ws;
  float*          xproj  = (float*)w;          w += alignup((size_t)CH*64*4096*4);
  unsigned short* in_bf  = (unsigned short*)w; w += alignup((size_t)CH*64*1024*2);
  unsigned short* wih_bf = (unsigned short*)w; w += alignup((size_t)4096*1024*2);
  unsigned short* whh_bf = (unsigned short*)w; w += alignup((size_t)4096*1024*2);
  unsigned short* hhist  = (unsigned short*)w; w += alignup(hhist_bytes);
  float*          cst    = (float*)w;

  // sentinel-fill the whole h history (slot 0 overwritten by init_state)
  hipMemsetAsync(hhist, 0x7F, hhist_bytes, stream);

  cvt_bf16<<<4096, 256, 0, stream>>>(wih, wih_bf, 4096*1024/4);
  cvt_bf16<<<4096, 256, 0, stream>>>(whh, whh_bf, 4096*1024/4);
  init_state<<<256, 256, 0, stream>>>(h0, c0, hhist, cst);

  const int nch = SEQ / CH;
  for (int ci = 0; ci < nch; ++ci){
    const int t0 = ci * CH;
    const int n4 = CH*64*1024/4;
    cvt_bf16<<<(n4+255)/256, 256, 0, stream>>>(inp + (size_t)t0*65536, in_bf, n4);
    gemm_xproj<<<dim3((CH*64/128)*32), 256, 0, stream>>>(in_bf, wih_bf, bih, bhh,
                                                         xproj, CH*64);
    lstm_rec<<<dim3(64), dim3(512), 0, stream>>>(whh_bf, xproj, hhist, cst, outp,
                                                 t0, CH);
  }
}

// Round 6
// 3847.523 us; speedup vs baseline: 1.3712x; 1.3712x over previous
//
#include <hip/hip_runtime.h>
#include <stdint.h>

#define SEQ    512
#define NBATCH 64
#define HID    1024
#define GDIM   4096

typedef __attribute__((ext_vector_type(4))) float          f32x4;
typedef __attribute__((ext_vector_type(8))) short          s16x8;
typedef __attribute__((ext_vector_type(4))) unsigned short u16x4;
typedef __attribute__((ext_vector_type(4))) unsigned int   u32x4;

#define MFMA_BF16(a,b,c) __builtin_amdgcn_mfma_f32_16x16x32_bf16((a),(b),(c),0,0,0)

__device__ __forceinline__ unsigned short f2bf(float f){
  union { float f; unsigned u; } v; v.f = f;
  unsigned r = v.u + 0x7fffu + ((v.u >> 16) & 1u);
  return (unsigned short)(r >> 16);
}

__device__ __forceinline__ void gload_lds16(const void* g, void* l){
  __builtin_amdgcn_global_load_lds((const __attribute__((address_space(1))) void*)g,
                                   (__attribute__((address_space(3))) void*)l,
                                   16, 0, 0);
}

// ---------------- fp32 -> bf16 bulk convert (n4 = elements/4) ----------------
__global__ __launch_bounds__(256) void cvt_bf16(const float* __restrict__ s,
                                                unsigned short* __restrict__ d, int n4){
  int i = blockIdx.x*256 + threadIdx.x;
  if (i >= n4) return;
  f32x4 v = *(const f32x4*)(s + (size_t)i*4);
  u16x4 o;
  o[0]=f2bf(v[0]); o[1]=f2bf(v[1]); o[2]=f2bf(v[2]); o[3]=f2bf(v[3]);
  *(u16x4*)(d + (size_t)i*4) = o;
}

// ---------------- init: h0 -> hring slot 0 (bf16, linear), c0 -> cstate ----
__global__ __launch_bounds__(256) void init_state(const float* __restrict__ h0,
                                                  const float* __restrict__ c0,
                                                  unsigned short* __restrict__ hring,
                                                  float* __restrict__ cstate){
  int i = blockIdx.x*256 + threadIdx.x;   // 65536 total
  hring[i]  = f2bf(h0[i]);
  cstate[i] = c0[i];
}

// ---------------- x_proj GEMM: C[M][4096] = A[M][1024] * Bw[4096][1024]^T + bias ----
__global__ __launch_bounds__(256,1) void gemm_xproj(
    const unsigned short* __restrict__ A,   // bf16 [M][1024]
    const unsigned short* __restrict__ Bw,  // bf16 [4096][1024]
    const float* __restrict__ bih, const float* __restrict__ bhh,
    float* __restrict__ C, int M)
{
  __shared__ unsigned short Al[2][128*64];
  __shared__ unsigned short Bl[2][128*64];

  const int bm = blockIdx.x >> 5;
  const int bn = blockIdx.x & 31;
  const int tid = threadIdx.x;
  const int wv = tid >> 6, l = tid & 63;
  const int wm = wv >> 1, wn = wv & 1;
  const int c16 = l & 15, rq = l >> 4;

  const unsigned short* Ab = A  + (size_t)bm*128*1024;
  const unsigned short* Bb = Bw + (size_t)bn*128*1024;

  f32x4 acc[4][4];
#pragma unroll
  for (int i=0;i<4;++i)
#pragma unroll
    for (int j=0;j<4;++j) acc[i][j] = (f32x4){0.f,0.f,0.f,0.f};

  auto stage = [&](int buf, int kt){
    const int k0 = kt*64;
    const int rsub = wv*8 + (l>>3);
    const int col  = (l&7)*8;
#pragma unroll
    for (int is=0; is<4; ++is){
      const int row = is*32 + rsub;
      gload_lds16(Ab + (size_t)row*1024 + k0 + col, &Al[buf][row*64 + col]);
      gload_lds16(Bb + (size_t)row*1024 + k0 + col, &Bl[buf][row*64 + col]);
    }
  };

  stage(0, 0);
  asm volatile("s_waitcnt vmcnt(0)" ::: "memory");
  __syncthreads();

  for (int kt = 0; kt < 16; ++kt){
    const int cur = kt & 1;
    if (kt < 15) stage(cur^1, kt+1);
#pragma unroll
    for (int ks=0; ks<2; ++ks){
      s16x8 afr[4], bfr[4];
#pragma unroll
      for (int mi=0;mi<4;++mi)
        afr[mi] = *(const s16x8*)&Al[cur][(wm*64 + mi*16 + c16)*64 + ks*32 + rq*8];
#pragma unroll
      for (int ni=0;ni<4;++ni)
        bfr[ni] = *(const s16x8*)&Bl[cur][(wn*64 + ni*16 + c16)*64 + ks*32 + rq*8];
#pragma unroll
      for (int mi=0;mi<4;++mi)
#pragma unroll
        for (int ni=0;ni<4;++ni)
          acc[mi][ni] = MFMA_BF16(afr[mi], bfr[ni], acc[mi][ni]);
    }
    asm volatile("s_waitcnt vmcnt(0)" ::: "memory");
    __syncthreads();
  }

  const int crow0 = bm*128 + wm*64;
  const int ccol0 = bn*128 + wn*64;
#pragma unroll
  for (int ni=0;ni<4;++ni){
    const int col = ccol0 + ni*16 + c16;
    const float bsum = bih[col] + bhh[col];
#pragma unroll
    for (int mi=0;mi<4;++mi){
      const int row = crow0 + mi*16 + rq*4;
#pragma unroll
      for (int r=0;r<4;++r)
        C[(size_t)(row+r)*GDIM + col] = acc[mi][ni][r] + bsum;
    }
  }
}

// ---------------- persistent recurrence over one chunk of timesteps ----------------
// 64 blocks x 512 threads. Block p owns hidden cols [16p,16p+16) -> 64 gate rows.
// Per-producer slice flags: block p stores its 2KB h-slice (sc0 sc1, LLC) then
// flag[p]=t+1. Consumer group g (8 threads) polls flag[g] >= t and immediately
// loads producer g's slice -> early slices stream while stragglers finish.
// 2-slot h ring (slot = t&1): safe because a producer can't overwrite slot s
// (h^{t+2}) before all blocks finished reading h^t from s (dataflow proof).
__global__ __launch_bounds__(512,2) void lstm_rec(
    const unsigned short* __restrict__ whhb,   // bf16 [4096][1024]
    const float* __restrict__ xproj,           // fp32 [nsteps*64][4096]
    unsigned short* __restrict__ hring,        // bf16 [2][64*1024] (linear)
    float* __restrict__ cstate,                // fp32 [64*1024]
    float* __restrict__ outp,                  // fp32 d_out base
    unsigned int* __restrict__ bar,            // 64 flags, stride 32 uints
    int t0, int nsteps)
{
  const int tid = threadIdx.x;
  const int wv = tid >> 6, l = tid & 63;
  const int kh = wv & 1, rh = (wv >> 1) & 1, mh = wv >> 2;
  const int c16 = l & 15, rq = l >> 4;
  const int hc0 = blockIdx.x * 16;
  const int eb = tid >> 3, ej = tid & 7;      // epilogue (batch, col)
  const int sg = tid >> 3, kg = tid & 7;      // slice group / lane-in-group

  __shared__ s16x8 hls4[8192];                // 128 KB staged h (swizzled chunks)
  __shared__ float part[64*67];               // 17.2 KB partials

  // ---- W_hh slice -> registers: n_local = j*4 + g (j col-local, g gate)
  s16x8 breg[2][16];
#pragma unroll
  for (int nt = 0; nt < 2; ++nt)
#pragma unroll
    for (int ks = 0; ks < 16; ++ks){
      const int n = rh*32 + nt*16 + c16;
      const int grow = (n & 3)*HID + hc0 + (n >> 2);
      const int k = kh*512 + ks*32 + rq*8;
      breg[nt][ks] = *(const s16x8*)(whhb + (size_t)grow*HID + k);
    }

  float creg0 = cstate[(size_t)eb*HID + hc0 + ej];
  float creg1 = cstate[(size_t)eb*HID + hc0 + ej + 8];
  float xpA[4], xpB[4];
#pragma unroll
  for (int g = 0; g < 4; ++g){
    xpA[g] = xproj[(size_t)eb*GDIM + g*HID + hc0 + ej];
    xpB[g] = xproj[(size_t)eb*GDIM + g*HID + hc0 + ej + 8];
  }

  for (int t = t0; t < t0 + nsteps; ++t){
    // ---- poll producer sg's flag (h^t ready), then load its 2KB slice
    {
      const unsigned int* fq = bar + (sg << 5);
      unsigned int fv; int spins = 0;
      do {
        asm volatile("global_load_dword %0, %1, off sc0 sc1\n\ts_waitcnt vmcnt(0)"
                     : "=v"(fv) : "v"(fq) : "memory");
      } while (fv < (unsigned int)t && ++spins < (1 << 17));

      const unsigned short* sbase = hring + (size_t)(t & 1)*65536 + sg*16;
      u32x4 tmp[16];
#pragma unroll
      for (int i = 0; i < 16; ++i){
        const int j = i*8 + kg;                 // 0..127
        const unsigned short* p = sbase + (size_t)(j >> 1)*1024 + (j & 1)*8;
        asm volatile("global_load_dwordx4 %0, %1, off sc0 sc1"
                     : "=v"(tmp[i]) : "v"(p));
      }
      asm volatile("s_waitcnt vmcnt(0)" ::: "memory");
      __builtin_amdgcn_sched_barrier(0);
#pragma unroll
      for (int i = 0; i < 16; ++i){
        const int j = i*8 + kg;
        const int b = j >> 1, c = sg*2 + (j & 1);
        hls4[b*128 + (c ^ (b & 7))] = __builtin_bit_cast(s16x8, tmp[i]);
      }
    }
    __syncthreads();

    // ---- MFMA: acc[msub][nt] over this wave's (batch-half, row-half, K-half)
    f32x4 acc[2][2];
#pragma unroll
    for (int ms = 0; ms < 2; ++ms)
#pragma unroll
      for (int nt = 0; nt < 2; ++nt) acc[ms][nt] = (f32x4){0.f,0.f,0.f,0.f};

#pragma unroll
    for (int ms = 0; ms < 2; ++ms){
      const int bl = mh*32 + ms*16 + c16;       // batch row in LDS
      const int bsw = bl & 7;
      s16x8 af[16];
#pragma unroll
      for (int ks = 0; ks < 16; ++ks)
        af[ks] = hls4[bl*128 + ((kh*64 + ks*4 + rq) ^ bsw)];
#pragma unroll
      for (int ks = 0; ks < 16; ++ks){
        acc[ms][0] = MFMA_BF16(af[ks], breg[0][ks], acc[ms][0]);
        acc[ms][1] = MFMA_BF16(af[ks], breg[1][ks], acc[ms][1]);
      }
    }

    // ---- K-half reduction through LDS: kh=0 writes, kh=1 adds
    if (kh == 0){
#pragma unroll
      for (int ms = 0; ms < 2; ++ms)
#pragma unroll
        for (int nt = 0; nt < 2; ++nt)
#pragma unroll
          for (int r = 0; r < 4; ++r)
            part[(mh*32 + ms*16 + rq*4 + r)*67 + rh*32 + nt*16 + c16] = acc[ms][nt][r];
    }
    __syncthreads();
    if (kh == 1){
#pragma unroll
      for (int ms = 0; ms < 2; ++ms)
#pragma unroll
        for (int nt = 0; nt < 2; ++nt)
#pragma unroll
          for (int r = 0; r < 4; ++r)
            part[(mh*32 + ms*16 + rq*4 + r)*67 + rh*32 + nt*16 + c16] += acc[ms][nt][r];
    }
    __syncthreads();

    // ---- epilogue: thread -> (batch eb, cols ej and ej+8)
    const float vi0 = part[eb*67 + ej*4 + 0] + xpA[0];
    const float vf0 = part[eb*67 + ej*4 + 1] + xpA[1];
    const float vg0 = part[eb*67 + ej*4 + 2] + xpA[2];
    const float vo0 = part[eb*67 + ej*4 + 3] + xpA[3];
    const float vi1 = part[eb*67 + 32 + ej*4 + 0] + xpB[0];
    const float vf1 = part[eb*67 + 32 + ej*4 + 1] + xpB[1];
    const float vg1 = part[eb*67 + 32 + ej*4 + 2] + xpB[2];
    const float vo1 = part[eb*67 + 32 + ej*4 + 3] + xpB[3];

    const float i0 = 1.f/(1.f + __expf(-vi0)), f0 = 1.f/(1.f + __expf(-vf0));
    const float g0 = tanhf(vg0),               o0 = 1.f/(1.f + __expf(-vo0));
    const float i1 = 1.f/(1.f + __expf(-vi1)), f1 = 1.f/(1.f + __expf(-vf1));
    const float g1 = tanhf(vg1),               o1 = 1.f/(1.f + __expf(-vo1));
    creg0 = f0*creg0 + i0*g0;
    creg1 = f1*creg1 + i1*g1;
    const float h0v = o0 * tanhf(creg0);
    const float h1v = o1 * tanhf(creg1);

    // ---- h slice store FIRST (critical path): 2B write-through to LLC
    {
      const unsigned short hb0 = f2bf(h0v), hb1 = f2bf(h1v);
      const unsigned short* hp = hring + (size_t)((t+1) & 1)*65536
                               + (size_t)eb*HID + hc0 + ej;
      asm volatile("global_store_short %0, %1, off sc0 sc1"
                   :: "v"(hp), "v"(hb0) : "memory");
      asm volatile("global_store_short %0, %1, off sc0 sc1"
                   :: "v"(hp + 8), "v"(hb1) : "memory");
    }
    asm volatile("s_waitcnt vmcnt(0)" ::: "memory");   // slice at LLC
    __syncthreads();
    if (tid == 0){
      unsigned int* fp = bar + (blockIdx.x << 5);
      unsigned int fv = (unsigned int)(t + 1);
      asm volatile("global_store_dword %0, %1, off sc0 sc1"
                   :: "v"(fp), "v"(fv) : "memory");
    }

    // ---- off-critical-path: outputs, last-step state, xproj prefetch
    const size_t oidx = (size_t)eb*HID + hc0 + ej;
    outp[(size_t)t*65536 + oidx]     = h0v;
    outp[(size_t)t*65536 + oidx + 8] = h1v;
    if (t == SEQ-1){
      outp[(size_t)SEQ*65536 + oidx]             = h0v;
      outp[(size_t)SEQ*65536 + oidx + 8]         = h1v;
      outp[(size_t)SEQ*65536 + 65536 + oidx]     = creg0;
      outp[(size_t)SEQ*65536 + 65536 + oidx + 8] = creg1;
    }
    if (t+1 < t0 + nsteps){
      const size_t xrow = (size_t)(t+1 - t0)*NBATCH + eb;
#pragma unroll
      for (int g = 0; g < 4; ++g){
        xpA[g] = xproj[xrow*GDIM + g*HID + hc0 + ej];
        xpB[g] = xproj[xrow*GDIM + g*HID + hc0 + ej + 8];
      }
    }
  }

  cstate[(size_t)eb*HID + hc0 + ej]     = creg0;
  cstate[(size_t)eb*HID + hc0 + ej + 8] = creg1;
}

// ---------------------------------------------------------------------------
extern "C" void kernel_launch(void* const* d_in, const int* in_sizes, int n_in,
                              void* d_out, int out_size, void* d_ws, size_t ws_size,
                              hipStream_t stream)
{
  const float* inp = (const float*)d_in[0];
  const float* wih = (const float*)d_in[1];
  const float* whh = (const float*)d_in[2];
  const float* bih = (const float*)d_in[3];
  const float* bhh = (const float*)d_in[4];
  const float* h0  = (const float*)d_in[5];
  const float* c0  = (const float*)d_in[6];
  float* outp = (float*)d_out;

  auto alignup = [](size_t x){ return (x + 255) & ~(size_t)255; };
  auto need = [&](size_t ch)->size_t{
    size_t s = 0;
    s += alignup(ch*64*4096*4);          // xproj chunk
    s += alignup(ch*64*1024*2);          // in_bf16 chunk
    s += alignup((size_t)4096*1024*2);   // wih_bf16
    s += alignup((size_t)4096*1024*2);   // whh_bf16
    s += alignup((size_t)2*64*1024*2);   // h ring (2 slots)
    s += alignup((size_t)64*1024*4);     // cstate
    s += alignup((size_t)64*32*4);       // flags
    return s;
  };
  int CH = 512;
  while (CH > 2 && need(CH) > ws_size) CH >>= 1;

  char* w = (char*)d_ws;
  float*          xproj  = (float*)w;          w += alignup((size_t)CH*64*4096*4);
  unsigned short* in_bf  = (unsigned short*)w; w += alignup((size_t)CH*64*1024*2);
  unsigned short* wih_bf = (unsigned short*)w; w += alignup((size_t)4096*1024*2);
  unsigned short* whh_bf = (unsigned short*)w; w += alignup((size_t)4096*1024*2);
  unsigned short* hring  = (unsigned short*)w; w += alignup((size_t)2*64*1024*2);
  float*          cst    = (float*)w;          w += alignup((size_t)64*1024*4);
  unsigned int*   bar    = (unsigned int*)w;

  hipMemsetAsync(bar, 0, 64*32*4, stream);

  cvt_bf16<<<4096, 256, 0, stream>>>(wih, wih_bf, 4096*1024/4);
  cvt_bf16<<<4096, 256, 0, stream>>>(whh, whh_bf, 4096*1024/4);
  init_state<<<256, 256, 0, stream>>>(h0, c0, hring, cst);

  const int nch = SEQ / CH;
  for (int ci = 0; ci < nch; ++ci){
    const int t0 = ci * CH;
    const int n4 = CH*64*1024/4;
    cvt_bf16<<<(n4+255)/256, 256, 0, stream>>>(inp + (size_t)t0*65536, in_bf, n4);
    gemm_xproj<<<dim3((CH*64/128)*32), 256, 0, stream>>>(in_bf, wih_bf, bih, bhh,
                                                         xproj, CH*64);
    lstm_rec<<<dim3(64), dim3(512), 0, stream>>>(whh_bf, xproj, hring, cst, outp,
                                                 bar, t0, CH);
  }
}

// Round 7
// 3041.709 us; speedup vs baseline: 1.7345x; 1.2649x over previous
//
#include <hip/hip_runtime.h>
#include <stdint.h>

#define SEQ    512
#define NBATCH 64
#define HID    1024
#define GDIM   4096

typedef __attribute__((ext_vector_type(4))) float          f32x4;
typedef __attribute__((ext_vector_type(8))) short          s16x8;
typedef __attribute__((ext_vector_type(4))) unsigned short u16x4;
typedef __attribute__((ext_vector_type(4))) unsigned int   u32x4;

#define MFMA_BF16(a,b,c) __builtin_amdgcn_mfma_f32_16x16x32_bf16((a),(b),(c),0,0,0)

__device__ __forceinline__ unsigned short f2bf(float f){
  union { float f; unsigned u; } v; v.f = f;
  unsigned r = v.u + 0x7fffu + ((v.u >> 16) & 1u);
  return (unsigned short)(r >> 16);
}

__device__ __forceinline__ void gload_lds16(const void* g, void* l){
  __builtin_amdgcn_global_load_lds((const __attribute__((address_space(1))) void*)g,
                                   (__attribute__((address_space(3))) void*)l,
                                   16, 0, 0);
}

// ---------------- fp32 -> bf16 bulk convert (n4 = elements/4) ----------------
__global__ __launch_bounds__(256) void cvt_bf16(const float* __restrict__ s,
                                                unsigned short* __restrict__ d, int n4){
  int i = blockIdx.x*256 + threadIdx.x;
  if (i >= n4) return;
  f32x4 v = *(const f32x4*)(s + (size_t)i*4);
  u16x4 o;
  o[0]=f2bf(v[0]); o[1]=f2bf(v[1]); o[2]=f2bf(v[2]); o[3]=f2bf(v[3]);
  *(u16x4*)(d + (size_t)i*4) = o;
}

// ---------------- init: h0 -> hring slot 0 (bf16, LINEAR), c0 -> cstate ----
__global__ __launch_bounds__(256) void init_state(const float* __restrict__ h0,
                                                  const float* __restrict__ c0,
                                                  unsigned short* __restrict__ hring,
                                                  float* __restrict__ cstate){
  int i = blockIdx.x*256 + threadIdx.x;   // 65536 total
  hring[i]  = f2bf(h0[i]);
  cstate[i] = c0[i];
}

// ---------------- x_proj GEMM: C[M][4096] = A[M][1024] * Bw[4096][1024]^T + bias ----
__global__ __launch_bounds__(256,1) void gemm_xproj(
    const unsigned short* __restrict__ A,   // bf16 [M][1024]
    const unsigned short* __restrict__ Bw,  // bf16 [4096][1024]
    const float* __restrict__ bih, const float* __restrict__ bhh,
    float* __restrict__ C, int M)
{
  __shared__ unsigned short Al[2][128*64];
  __shared__ unsigned short Bl[2][128*64];

  const int bm = blockIdx.x >> 5;
  const int bn = blockIdx.x & 31;
  const int tid = threadIdx.x;
  const int wv = tid >> 6, l = tid & 63;
  const int wm = wv >> 1, wn = wv & 1;
  const int c16 = l & 15, rq = l >> 4;

  const unsigned short* Ab = A  + (size_t)bm*128*1024;
  const unsigned short* Bb = Bw + (size_t)bn*128*1024;

  f32x4 acc[4][4];
#pragma unroll
  for (int i=0;i<4;++i)
#pragma unroll
    for (int j=0;j<4;++j) acc[i][j] = (f32x4){0.f,0.f,0.f,0.f};

  auto stage = [&](int buf, int kt){
    const int k0 = kt*64;
    const int rsub = wv*8 + (l>>3);
    const int col  = (l&7)*8;
#pragma unroll
    for (int is=0; is<4; ++is){
      const int row = is*32 + rsub;
      gload_lds16(Ab + (size_t)row*1024 + k0 + col, &Al[buf][row*64 + col]);
      gload_lds16(Bb + (size_t)row*1024 + k0 + col, &Bl[buf][row*64 + col]);
    }
  };

  stage(0, 0);
  asm volatile("s_waitcnt vmcnt(0)" ::: "memory");
  __syncthreads();

  for (int kt = 0; kt < 16; ++kt){
    const int cur = kt & 1;
    if (kt < 15) stage(cur^1, kt+1);
#pragma unroll
    for (int ks=0; ks<2; ++ks){
      s16x8 afr[4], bfr[4];
#pragma unroll
      for (int mi=0;mi<4;++mi)
        afr[mi] = *(const s16x8*)&Al[cur][(wm*64 + mi*16 + c16)*64 + ks*32 + rq*8];
#pragma unroll
      for (int ni=0;ni<4;++ni)
        bfr[ni] = *(const s16x8*)&Bl[cur][(wn*64 + ni*16 + c16)*64 + ks*32 + rq*8];
#pragma unroll
      for (int mi=0;mi<4;++mi)
#pragma unroll
        for (int ni=0;ni<4;++ni)
          acc[mi][ni] = MFMA_BF16(afr[mi], bfr[ni], acc[mi][ni]);
    }
    asm volatile("s_waitcnt vmcnt(0)" ::: "memory");
    __syncthreads();
  }

  const int crow0 = bm*128 + wm*64;
  const int ccol0 = bn*128 + wn*64;
#pragma unroll
  for (int ni=0;ni<4;++ni){
    const int col = ccol0 + ni*16 + c16;
    const float bsum = bih[col] + bhh[col];
#pragma unroll
    for (int mi=0;mi<4;++mi){
      const int row = crow0 + mi*16 + rq*4;
#pragma unroll
      for (int r=0;r<4;++r)
        C[(size_t)(row+r)*GDIM + col] = acc[mi][ni][r] + bsum;
    }
  }
}

// ---------------- persistent recurrence, 2-D batch x hidden decomposition ------
// 256 blocks x 512 threads = 4 batch-groups (bq: 16 rows) x 64 hidden-groups
// (hg: 16 cols -> 64 gate rows). Block (bq,hg) reads only h[bq's 16 rows][1024]
// = 32 KB/step. Sync domain = 64 blocks sharing bq (4 independent domains).
// Flags are monotone per-producer counters; each thread polls only the 4
// producers covering its own chunks, then loads them (no poll barrier).
// Waves: kq = wv>>1 (K quarter, 256), rh = wv&1 (gate-row half, 32 rows).
__global__ __launch_bounds__(512,1) void lstm_rec(
    const unsigned short* __restrict__ whhb,   // bf16 [4096][1024]
    const float* __restrict__ xproj,           // fp32 [nsteps*64][4096]
    unsigned short* __restrict__ hring,        // bf16 [2][64*1024] (linear)
    float* __restrict__ cstate,                // fp32 [64*1024]
    float* __restrict__ outp,                  // fp32 d_out base
    unsigned int* __restrict__ bar,            // [4*64] flags, stride 32 uints
    int t0, int nsteps)
{
  const int tid = threadIdx.x;
  const int wv = tid >> 6, l = tid & 63;
  const int kq = wv >> 1, rh = wv & 1;
  const int c16 = l & 15, rq = l >> 4;
  const int bq = blockIdx.x >> 6;             // batch group 0..3
  const int hg = blockIdx.x & 63;             // hidden group 0..63
  const int hc0 = hg * 16;
  const int b0  = bq * 16;
  const int eb = tid >> 4, ec = tid & 15;     // epilogue (batch,col), tid<256
  const int sb = tid >> 5, cl0 = tid & 31;    // staging (batch row, chunk base)

  __shared__ s16x8 hls[16*128];                         // 32 KB staged h
  __shared__ float part[8*16*33];                       // 16.9 KB partials
  __shared__ __align__(16) unsigned short hsh[16*16];   // 512 B h staging

  // ---- W_hh slice -> registers: n = rh*32 + nt*16 + c16 (gate row local),
  //      whh row = (n&3)*HID + hc0 + (n>>2); k = kq*256 + ks*32 + rq*8
  s16x8 breg[2][8];
#pragma unroll
  for (int nt = 0; nt < 2; ++nt)
#pragma unroll
    for (int ks = 0; ks < 8; ++ks){
      const int n = rh*32 + nt*16 + c16;
      const int grow = (n & 3)*HID + hc0 + (n >> 2);
      const int k = kq*256 + ks*32 + rq*8;
      breg[nt][ks] = *(const s16x8*)(whhb + (size_t)grow*HID + k);
    }

  float creg = 0.f, xp[4] = {0.f,0.f,0.f,0.f};
  if (tid < 256){
    creg = cstate[(size_t)(b0+eb)*HID + hc0 + ec];
#pragma unroll
    for (int g = 0; g < 4; ++g)
      xp[g] = xproj[(size_t)(b0+eb)*GDIM + g*HID + hc0 + ec];
  }

  // flag addresses for this thread's 4 producers: p_i = (cl0>>1) + 16*i
  const unsigned int* fq0 = bar + ((bq*64 + (cl0 >> 1) +  0) << 5);
  const unsigned int* fq1 = bar + ((bq*64 + (cl0 >> 1) + 16) << 5);
  const unsigned int* fq2 = bar + ((bq*64 + (cl0 >> 1) + 32) << 5);
  const unsigned int* fq3 = bar + ((bq*64 + (cl0 >> 1) + 48) << 5);

  for (int t = t0; t < t0 + nsteps; ++t){
    // ---- per-thread flag poll (only the 4 producers of my chunks)
    {
      unsigned f0, f1, f2, f3; int spins = 0;
      const unsigned ut = (unsigned)t;
      do {
        asm volatile("global_load_dword %0, %4, off sc0 sc1\n\t"
                     "global_load_dword %1, %5, off sc0 sc1\n\t"
                     "global_load_dword %2, %6, off sc0 sc1\n\t"
                     "global_load_dword %3, %7, off sc0 sc1\n\t"
                     "s_waitcnt vmcnt(0)"
                     : "=v"(f0), "=v"(f1), "=v"(f2), "=v"(f3)
                     : "v"(fq0), "v"(fq1), "v"(fq2), "v"(fq3) : "memory");
        if (f0 >= ut && f1 >= ut && f2 >= ut && f3 >= ut) break;
        if (++spins > 6) __builtin_amdgcn_s_sleep(1);
      } while (spins < (1 << 17));
    }
    // ---- load my 4 chunks (linear global), write LDS at swizzled position
    {
      const unsigned short* gb = hring + (size_t)(t & 1)*65536
                               + (size_t)(b0 + sb)*HID;
      u32x4 tmp[4];
#pragma unroll
      for (int i = 0; i < 4; ++i){
        const unsigned short* p = gb + (cl0 + 32*i)*8;
        asm volatile("global_load_dwordx4 %0, %1, off sc0 sc1"
                     : "=v"(tmp[i]) : "v"(p));
      }
      asm volatile("s_waitcnt vmcnt(0)" ::: "memory");
      __builtin_amdgcn_sched_barrier(0);
#pragma unroll
      for (int i = 0; i < 4; ++i){
        const int cl = cl0 + 32*i;
        hls[sb*128 + ((cl & ~7) | ((cl & 7) ^ (sb & 7)))] =
            __builtin_bit_cast(s16x8, tmp[i]);
      }
    }
    __syncthreads();                                   // B1: hls ready

    // ---- MFMA: this wave covers (K quarter kq, row half rh), all 16 batch
    f32x4 acc0 = (f32x4){0.f,0.f,0.f,0.f};
    f32x4 acc1 = (f32x4){0.f,0.f,0.f,0.f};
    {
      s16x8 af[8];
#pragma unroll
      for (int ks = 0; ks < 8; ++ks){
        const int c = kq*32 + ks*4 + rq;
        af[ks] = hls[c16*128 + ((c & ~7) | ((c & 7) ^ (c16 & 7)))];
      }
#pragma unroll
      for (int ks = 0; ks < 8; ++ks){
        acc0 = MFMA_BF16(af[ks], breg[0][ks], acc0);
        acc1 = MFMA_BF16(af[ks], breg[1][ks], acc1);
      }
    }
    // part[wv][batch = rq*4+r][nl = nt*16+c16], stride 33
#pragma unroll
    for (int r = 0; r < 4; ++r){
      part[wv*528 + (rq*4+r)*33 +      c16] = acc0[r];
      part[wv*528 + (rq*4+r)*33 + 16 + c16] = acc1[r];
    }
    __syncthreads();                                   // B2: partials ready

    // ---- epilogue (256 threads): reduce 4 K-quarters, activations, state
    float hval = 0.f;
    if (tid < 256){
      float v[4];
#pragma unroll
      for (int g = 0; g < 4; ++g){
        const int row = ec*4 + g;
        const int pl = (row >> 5);                     // row half
        const int nl = row & 31;
        v[g] = xp[g]
             + part[(0*2 + pl)*528 + eb*33 + nl]
             + part[(1*2 + pl)*528 + eb*33 + nl]
             + part[(2*2 + pl)*528 + eb*33 + nl]
             + part[(3*2 + pl)*528 + eb*33 + nl];
      }
      const float ig = 1.f/(1.f + __expf(-v[0]));
      const float fg = 1.f/(1.f + __expf(-v[1]));
      const float gg = tanhf(v[2]);
      const float og = 1.f/(1.f + __expf(-v[3]));
      creg = fg*creg + ig*gg;
      hval = og * tanhf(creg);
      hsh[eb*16 + ec] = f2bf(hval);
    }
    __syncthreads();                                   // B3: hsh ready

    // ---- wave 0 lanes 0-31: h slice store -> drain -> flag (intra-wave order)
    if (tid < 32){
      const int row = tid >> 1, half = tid & 1;
      const unsigned short* hp = hring + (size_t)((t+1) & 1)*65536
                               + (size_t)(b0 + row)*HID + hc0 + half*8;
      u32x4 hv = *(const u32x4*)&hsh[row*16 + half*8];
      asm volatile("global_store_dwordx4 %0, %1, off sc0 sc1"
                   :: "v"(hp), "v"(hv) : "memory");
      asm volatile("s_waitcnt vmcnt(0)" ::: "memory");
      if (tid == 0){
        unsigned int* fp = bar + ((bq*64 + hg) << 5);
        unsigned int fv = (unsigned int)(t + 1);
        asm volatile("global_store_dword %0, %1, off sc0 sc1"
                     :: "v"(fp), "v"(fv) : "memory");
      }
    }

    // ---- off critical path: outputs, final state, xproj prefetch
    if (tid < 256){
      const size_t oidx = (size_t)(b0+eb)*HID + hc0 + ec;
      outp[(size_t)t*65536 + oidx] = hval;
      if (t == SEQ-1){
        outp[(size_t)SEQ*65536 + oidx]         = hval;   // h_last
        outp[(size_t)SEQ*65536 + 65536 + oidx] = creg;   // c_last
      }
      if (t+1 < t0 + nsteps){
        const size_t xrow = (size_t)(t+1 - t0)*NBATCH + (b0+eb);
#pragma unroll
        for (int g = 0; g < 4; ++g)
          xp[g] = xproj[xrow*GDIM + g*HID + hc0 + ec];
      }
    }
  }

  if (tid < 256)
    cstate[(size_t)(b0+eb)*HID + hc0 + ec] = creg;
}

// ---------------------------------------------------------------------------
extern "C" void kernel_launch(void* const* d_in, const int* in_sizes, int n_in,
                              void* d_out, int out_size, void* d_ws, size_t ws_size,
                              hipStream_t stream)
{
  const float* inp = (const float*)d_in[0];
  const float* wih = (const float*)d_in[1];
  const float* whh = (const float*)d_in[2];
  const float* bih = (const float*)d_in[3];
  const float* bhh = (const float*)d_in[4];
  const float* h0  = (const float*)d_in[5];
  const float* c0  = (const float*)d_in[6];
  float* outp = (float*)d_out;

  auto alignup = [](size_t x){ return (x + 255) & ~(size_t)255; };
  auto need = [&](size_t ch)->size_t{
    size_t s = 0;
    s += alignup(ch*64*4096*4);          // xproj chunk
    s += alignup(ch*64*1024*2);          // in_bf16 chunk
    s += alignup((size_t)4096*1024*2);   // wih_bf16
    s += alignup((size_t)4096*1024*2);   // whh_bf16
    s += alignup((size_t)2*64*1024*2);   // h ring (2 slots)
    s += alignup((size_t)64*1024*4);     // cstate
    s += alignup((size_t)256*32*4);      // flags
    return s;
  };
  int CH = 512;
  while (CH > 2 && need(CH) > ws_size) CH >>= 1;

  char* w = (char*)d_ws;
  float*          xproj  = (float*)w;          w += alignup((size_t)CH*64*4096*4);
  unsigned short* in_bf  = (unsigned short*)w; w += alignup((size_t)CH*64*1024*2);
  unsigned short* wih_bf = (unsigned short*)w; w += alignup((size_t)4096*1024*2);
  unsigned short* whh_bf = (unsigned short*)w; w += alignup((size_t)4096*1024*2);
  unsigned short* hring  = (unsigned short*)w; w += alignup((size_t)2*64*1024*2);
  float*          cst    = (float*)w;          w += alignup((size_t)64*1024*4);
  unsigned int*   bar    = (unsigned int*)w;

  hipMemsetAsync(bar, 0, 256*32*4, stream);

  cvt_bf16<<<4096, 256, 0, stream>>>(wih, wih_bf, 4096*1024/4);
  cvt_bf16<<<4096, 256, 0, stream>>>(whh, whh_bf, 4096*1024/4);
  init_state<<<256, 256, 0, stream>>>(h0, c0, hring, cst);

  const int nch = SEQ / CH;
  for (int ci = 0; ci < nch; ++ci){
    const int t0 = ci * CH;
    const int n4 = CH*64*1024/4;
    cvt_bf16<<<(n4+255)/256, 256, 0, stream>>>(inp + (size_t)t0*65536, in_bf, n4);
    gemm_xproj<<<dim3((CH*64/128)*32), 256, 0, stream>>>(in_bf, wih_bf, bih, bhh,
                                                         xproj, CH*64);
    lstm_rec<<<dim3(256), dim3(512), 0, stream>>>(whh_bf, xproj, hring, cst, outp,
                                                  bar, t0, CH);
  }
}

// Round 8
// 2203.364 us; speedup vs baseline: 2.3945x; 1.3805x over previous
//
#include <hip/hip_runtime.h>
#include <stdint.h>

#define SEQ    512
#define NBATCH 64
#define HID    1024
#define GDIM   4096

typedef __attribute__((ext_vector_type(4))) float          f32x4;
typedef __attribute__((ext_vector_type(8))) short          s16x8;
typedef __attribute__((ext_vector_type(4))) unsigned short u16x4;
typedef __attribute__((ext_vector_type(4))) unsigned int   u32x4;

#define MFMA_BF16(a,b,c) __builtin_amdgcn_mfma_f32_16x16x32_bf16((a),(b),(c),0,0,0)

__device__ __forceinline__ unsigned short f2bf(float f){
  union { float f; unsigned u; } v; v.f = f;
  unsigned r = v.u + 0x7fffu + ((v.u >> 16) & 1u);
  return (unsigned short)(r >> 16);
}

__device__ __forceinline__ void gload_lds16(const void* g, void* l){
  __builtin_amdgcn_global_load_lds((const __attribute__((address_space(1))) void*)g,
                                   (__attribute__((address_space(3))) void*)l,
                                   16, 0, 0);
}

// ---------------- fp32 -> bf16 bulk convert (n4 = elements/4) ----------------
__global__ __launch_bounds__(256) void cvt_bf16(const float* __restrict__ s,
                                                unsigned short* __restrict__ d, int n4){
  int i = blockIdx.x*256 + threadIdx.x;
  if (i >= n4) return;
  f32x4 v = *(const f32x4*)(s + (size_t)i*4);
  u16x4 o;
  o[0]=f2bf(v[0]); o[1]=f2bf(v[1]); o[2]=f2bf(v[2]); o[3]=f2bf(v[3]);
  *(u16x4*)(d + (size_t)i*4) = o;
}

// ---------------- init: h0 -> hring slot 0 (bf16, LINEAR), c0 -> cstate ----
__global__ __launch_bounds__(256) void init_state(const float* __restrict__ h0,
                                                  const float* __restrict__ c0,
                                                  unsigned short* __restrict__ hring,
                                                  float* __restrict__ cstate){
  int i = blockIdx.x*256 + threadIdx.x;   // 65536 total
  hring[i]  = f2bf(h0[i]);
  cstate[i] = c0[i];
}

// ---------------- x_proj GEMM: C[M][4096] = A[M][1024] * Bw[4096][1024]^T + bias ----
__global__ __launch_bounds__(256,1) void gemm_xproj(
    const unsigned short* __restrict__ A,   // bf16 [M][1024]
    const unsigned short* __restrict__ Bw,  // bf16 [4096][1024]
    const float* __restrict__ bih, const float* __restrict__ bhh,
    float* __restrict__ C, int M)
{
  __shared__ unsigned short Al[2][128*64];
  __shared__ unsigned short Bl[2][128*64];

  const int bm = blockIdx.x >> 5;
  const int bn = blockIdx.x & 31;
  const int tid = threadIdx.x;
  const int wv = tid >> 6, l = tid & 63;
  const int wm = wv >> 1, wn = wv & 1;
  const int c16 = l & 15, rq = l >> 4;

  const unsigned short* Ab = A  + (size_t)bm*128*1024;
  const unsigned short* Bb = Bw + (size_t)bn*128*1024;

  f32x4 acc[4][4];
#pragma unroll
  for (int i=0;i<4;++i)
#pragma unroll
    for (int j=0;j<4;++j) acc[i][j] = (f32x4){0.f,0.f,0.f,0.f};

  auto stage = [&](int buf, int kt){
    const int k0 = kt*64;
    const int rsub = wv*8 + (l>>3);
    const int col  = (l&7)*8;
#pragma unroll
    for (int is=0; is<4; ++is){
      const int row = is*32 + rsub;
      gload_lds16(Ab + (size_t)row*1024 + k0 + col, &Al[buf][row*64 + col]);
      gload_lds16(Bb + (size_t)row*1024 + k0 + col, &Bl[buf][row*64 + col]);
    }
  };

  stage(0, 0);
  asm volatile("s_waitcnt vmcnt(0)" ::: "memory");
  __syncthreads();

  for (int kt = 0; kt < 16; ++kt){
    const int cur = kt & 1;
    if (kt < 15) stage(cur^1, kt+1);
#pragma unroll
    for (int ks=0; ks<2; ++ks){
      s16x8 afr[4], bfr[4];
#pragma unroll
      for (int mi=0;mi<4;++mi)
        afr[mi] = *(const s16x8*)&Al[cur][(wm*64 + mi*16 + c16)*64 + ks*32 + rq*8];
#pragma unroll
      for (int ni=0;ni<4;++ni)
        bfr[ni] = *(const s16x8*)&Bl[cur][(wn*64 + ni*16 + c16)*64 + ks*32 + rq*8];
#pragma unroll
      for (int mi=0;mi<4;++mi)
#pragma unroll
        for (int ni=0;ni<4;++ni)
          acc[mi][ni] = MFMA_BF16(afr[mi], bfr[ni], acc[mi][ni]);
    }
    asm volatile("s_waitcnt vmcnt(0)" ::: "memory");
    __syncthreads();
  }

  const int crow0 = bm*128 + wm*64;
  const int ccol0 = bn*128 + wn*64;
#pragma unroll
  for (int ni=0;ni<4;++ni){
    const int col = ccol0 + ni*16 + c16;
    const float bsum = bih[col] + bhh[col];
#pragma unroll
    for (int mi=0;mi<4;++mi){
      const int row = crow0 + mi*16 + rq*4;
#pragma unroll
      for (int r=0;r<4;++r)
        C[(size_t)(row+r)*GDIM + col] = acc[mi][ni][r] + bsum;
    }
  }
}

// ---------------- persistent recurrence, 2-D batch x hidden decomposition ------
// 256 blocks x 512 threads = 4 batch-groups (bq: 16 rows) x 64 hidden-groups
// (hg: 16 cols -> 64 gate rows). Block (bq,hg) reads h[16 rows][1024] = 32 KB.
// Sync: monotone per-producer flags at LLC. ONLY WAVE 0 polls (lane l -> flag l)
// to avoid the R7 poll storm (512x4 pollers saturated the LLC); barrier B0
// releases the block. Producer: 32 lanes store h slice (16B), drain, flag.
__global__ __launch_bounds__(512,1) void lstm_rec(
    const unsigned short* __restrict__ whhb,   // bf16 [4096][1024]
    const float* __restrict__ xproj,           // fp32 [nsteps*64][4096]
    unsigned short* __restrict__ hring,        // bf16 [2][64*1024] (linear)
    float* __restrict__ cstate,                // fp32 [64*1024]
    float* __restrict__ outp,                  // fp32 d_out base
    unsigned int* __restrict__ bar,            // [4*64] flags, stride 32 uints
    int t0, int nsteps)
{
  const int tid = threadIdx.x;
  const int wv = tid >> 6, l = tid & 63;
  const int kq = wv >> 1, rh = wv & 1;
  const int c16 = l & 15, rq = l >> 4;
  const int bq = blockIdx.x >> 6;             // batch group 0..3
  const int hg = blockIdx.x & 63;             // hidden group 0..63
  const int hc0 = hg * 16;
  const int b0  = bq * 16;
  const int eb = tid >> 4, ec = tid & 15;     // epilogue (batch,col), tid<256
  const int sb = tid >> 5, cl0 = tid & 31;    // staging (batch row, chunk base)

  __shared__ s16x8 hls[16*128];                         // 32 KB staged h
  __shared__ float part[8*16*36];                       // 18.4 KB partials
  __shared__ __align__(16) unsigned short hsh[16*16];   // 512 B h staging

  // ---- W_hh slice -> registers: n = rh*32 + nt*16 + c16 (gate row local),
  //      whh row = (n&3)*HID + hc0 + (n>>2); k = kq*256 + ks*32 + rq*8
  s16x8 breg[2][8];
#pragma unroll
  for (int nt = 0; nt < 2; ++nt)
#pragma unroll
    for (int ks = 0; ks < 8; ++ks){
      const int n = rh*32 + nt*16 + c16;
      const int grow = (n & 3)*HID + hc0 + (n >> 2);
      const int k = kq*256 + ks*32 + rq*8;
      breg[nt][ks] = *(const s16x8*)(whhb + (size_t)grow*HID + k);
    }

  float creg = 0.f, xp[4] = {0.f,0.f,0.f,0.f};
  if (tid < 256){
    creg = cstate[(size_t)(b0+eb)*HID + hc0 + ec];
#pragma unroll
    for (int g = 0; g < 4; ++g)
      xp[g] = xproj[(size_t)(b0+eb)*GDIM + g*HID + hc0 + ec];
  }

  const unsigned int* myflag = bar + ((bq*64 + l) << 5);   // wave-0 poll target

  for (int t = t0; t < t0 + nsteps; ++t){
    // ---- wave 0: poll 64 domain flags (1 per lane), divergent spin
    if (wv == 0){
      unsigned fv; int spins = 0;
      const unsigned ut = (unsigned)t;
      do {
        asm volatile("global_load_dword %0, %1, off sc0 sc1\n\ts_waitcnt vmcnt(0)"
                     : "=v"(fv) : "v"(myflag) : "memory");
        if (fv >= ut) break;
        if (++spins > 4) __builtin_amdgcn_s_sleep(1);
      } while (spins < (1 << 17));
    }
    __syncthreads();                                   // B0: h^t ready

    // ---- load my 4 chunks (linear global), write LDS at swizzled position
    {
      const unsigned short* gb = hring + (size_t)(t & 1)*65536
                               + (size_t)(b0 + sb)*HID;
      u32x4 tmp[4];
#pragma unroll
      for (int i = 0; i < 4; ++i){
        const unsigned short* p = gb + (cl0 + 32*i)*8;
        asm volatile("global_load_dwordx4 %0, %1, off sc0 sc1"
                     : "=v"(tmp[i]) : "v"(p));
      }
      asm volatile("s_waitcnt vmcnt(0)" ::: "memory");
      __builtin_amdgcn_sched_barrier(0);
#pragma unroll
      for (int i = 0; i < 4; ++i){
        const int cl = cl0 + 32*i;
        hls[sb*128 + ((cl & ~7) | ((cl & 7) ^ (sb & 7)))] =
            __builtin_bit_cast(s16x8, tmp[i]);
      }
    }
    __syncthreads();                                   // B1: hls ready

    // ---- MFMA: this wave covers (K quarter kq, row half rh), all 16 batch
    f32x4 acc0 = (f32x4){0.f,0.f,0.f,0.f};
    f32x4 acc1 = (f32x4){0.f,0.f,0.f,0.f};
    {
      s16x8 af[8];
#pragma unroll
      for (int ks = 0; ks < 8; ++ks){
        const int c = kq*32 + ks*4 + rq;
        af[ks] = hls[c16*128 + ((c & ~7) | ((c & 7) ^ (c16 & 7)))];
      }
#pragma unroll
      for (int ks = 0; ks < 8; ++ks){
        acc0 = MFMA_BF16(af[ks], breg[0][ks], acc0);
        acc1 = MFMA_BF16(af[ks], breg[1][ks], acc1);
      }
    }
    // part[wv][batch = rq*4+r][nl = nt*16+c16], stride 36 (2-way banks = free)
#pragma unroll
    for (int r = 0; r < 4; ++r){
      part[wv*576 + (rq*4+r)*36 +      c16] = acc0[r];
      part[wv*576 + (rq*4+r)*36 + 16 + c16] = acc1[r];
    }
    __syncthreads();                                   // B2: partials ready

    // ---- epilogue (256 threads): reduce 4 K-quarters, activations, state
    float hval = 0.f;
    if (tid < 256){
      float v[4];
#pragma unroll
      for (int g = 0; g < 4; ++g){
        const int row = ec*4 + g;
        const int pl = (row >> 5);                     // row half
        const int nl = row & 31;
        v[g] = xp[g]
             + part[(0*2 + pl)*576 + eb*36 + nl]
             + part[(1*2 + pl)*576 + eb*36 + nl]
             + part[(2*2 + pl)*576 + eb*36 + nl]
             + part[(3*2 + pl)*576 + eb*36 + nl];
      }
      const float ig = 1.f/(1.f + __expf(-v[0]));
      const float fg = 1.f/(1.f + __expf(-v[1]));
      const float gg = tanhf(v[2]);
      const float og = 1.f/(1.f + __expf(-v[3]));
      creg = fg*creg + ig*gg;
      hval = og * tanhf(creg);
      hsh[eb*16 + ec] = f2bf(hval);
    }
    __syncthreads();                                   // B3: hsh ready

    // ---- critical path first: 32 lanes store h slice -> drain -> flag
    if (tid < 32){
      const int row = tid >> 1, half = tid & 1;
      const unsigned short* hp = hring + (size_t)((t+1) & 1)*65536
                               + (size_t)(b0 + row)*HID + hc0 + half*8;
      u32x4 hv = *(const u32x4*)&hsh[row*16 + half*8];
      asm volatile("global_store_dwordx4 %0, %1, off sc0 sc1"
                   :: "v"(hp), "v"(hv) : "memory");
      asm volatile("s_waitcnt vmcnt(0)" ::: "memory");
      if (tid == 0){
        unsigned int* fp = bar + ((bq*64 + hg) << 5);
        unsigned int fv = (unsigned int)(t + 1);
        asm volatile("global_store_dword %0, %1, off sc0 sc1"
                     :: "v"(fp), "v"(fv) : "memory");
      }
    }

    // ---- off critical path: outputs, final state, xproj prefetch
    if (tid < 256){
      const size_t oidx = (size_t)(b0+eb)*HID + hc0 + ec;
      outp[(size_t)t*65536 + oidx] = hval;
      if (t == SEQ-1){
        outp[(size_t)SEQ*65536 + oidx]         = hval;   // h_last
        outp[(size_t)SEQ*65536 + 65536 + oidx] = creg;   // c_last
      }
      if (t+1 < t0 + nsteps){
        const size_t xrow = (size_t)(t+1 - t0)*NBATCH + (b0+eb);
#pragma unroll
        for (int g = 0; g < 4; ++g)
          xp[g] = xproj[xrow*GDIM + g*HID + hc0 + ec];
      }
    }
  }

  if (tid < 256)
    cstate[(size_t)(b0+eb)*HID + hc0 + ec] = creg;
}

// ---------------------------------------------------------------------------
extern "C" void kernel_launch(void* const* d_in, const int* in_sizes, int n_in,
                              void* d_out, int out_size, void* d_ws, size_t ws_size,
                              hipStream_t stream)
{
  const float* inp = (const float*)d_in[0];
  const float* wih = (const float*)d_in[1];
  const float* whh = (const float*)d_in[2];
  const float* bih = (const float*)d_in[3];
  const float* bhh = (const float*)d_in[4];
  const float* h0  = (const float*)d_in[5];
  const float* c0  = (const float*)d_in[6];
  float* outp = (float*)d_out;

  auto alignup = [](size_t x){ return (x + 255) & ~(size_t)255; };
  auto need = [&](size_t ch)->size_t{
    size_t s = 0;
    s += alignup(ch*64*4096*4);          // xproj chunk
    s += alignup(ch*64*1024*2);          // in_bf16 chunk
    s += alignup((size_t)4096*1024*2);   // wih_bf16
    s += alignup((size_t)4096*1024*2);   // whh_bf16
    s += alignup((size_t)2*64*1024*2);   // h ring (2 slots)
    s += alignup((size_t)64*1024*4);     // cstate
    s += alignup((size_t)256*32*4);      // flags
    return s;
  };
  int CH = 512;
  while (CH > 2 && need(CH) > ws_size) CH >>= 1;

  char* w = (char*)d_ws;
  float*          xproj  = (float*)w;          w += alignup((size_t)CH*64*4096*4);
  unsigned short* in_bf  = (unsigned short*)w; w += alignup((size_t)CH*64*1024*2);
  unsigned short* wih_bf = (unsigned short*)w; w += alignup((size_t)4096*1024*2);
  unsigned short* whh_bf = (unsigned short*)w; w += alignup((size_t)4096*1024*2);
  unsigned short* hring  = (unsigned short*)w; w += alignup((size_t)2*64*1024*2);
  float*          cst    = (float*)w;          w += alignup((size_t)64*1024*4);
  unsigned int*   bar    = (unsigned int*)w;

  hipMemsetAsync(bar, 0, 256*32*4, stream);

  cvt_bf16<<<4096, 256, 0, stream>>>(wih, wih_bf, 4096*1024/4);
  cvt_bf16<<<4096, 256, 0, stream>>>(whh, whh_bf, 4096*1024/4);
  init_state<<<256, 256, 0, stream>>>(h0, c0, hring, cst);

  const int nch = SEQ / CH;
  for (int ci = 0; ci < nch; ++ci){
    const int t0 = ci * CH;
    const int n4 = CH*64*1024/4;
    cvt_bf16<<<(n4+255)/256, 256, 0, stream>>>(inp + (size_t)t0*65536, in_bf, n4);
    gemm_xproj<<<dim3((CH*64/128)*32), 256, 0, stream>>>(in_bf, wih_bf, bih, bhh,
                                                         xproj, CH*64);
    lstm_rec<<<dim3(256), dim3(512), 0, stream>>>(whh_bf, xproj, hring, cst, outp,
                                                  bar, t0, CH);
  }
}